// Round 1
// baseline (733.642 us; speedup 1.0000x reference)
//
#include <hip/hip_runtime.h>

// ---------------- problem constants ----------------
constexpr int Nn   = 100000;   // nodes
constexpr int Ee   = 1600000;  // edges
constexpr int D    = 128;      // hidden = input dim
constexpr int DOUT = 40;       // classifier out
constexpr int CAP  = 80;       // max in-degree bucket capacity (Poisson(16); P(deg>=80) ~ 1e-28)

// ---------------- edge dtype detect ----------------
// If edge_index is stored as int64, the odd 32-bit words are high words == 0
// (values in [0, 1e5)). If int32, odd words are random node ids (P(all 0) ~ 0).
__global__ void detect_layout(const int* __restrict__ ei, int* __restrict__ flag) {
    if (threadIdx.x == 0 && blockIdx.x == 0) {
        unsigned orv = 0;
        for (int j = 0; j < 256; ++j) orv |= (unsigned)ei[2 * j + 1];
        *flag = (orv == 0u) ? 1 : 0;  // 1 => int64 layout
    }
}

// ---------------- bucket build (counting) ----------------
__global__ __launch_bounds__(256) void build_buckets(const int* __restrict__ ei,
                                                     const int* __restrict__ flag,
                                                     int* __restrict__ cnt,
                                                     int* __restrict__ bucket) {
    int e = blockIdx.x * 256 + threadIdx.x;
    if (e >= Ee) return;
    int f = *flag;
    int s, d;
    if (f) { s = ei[2 * e]; d = ei[2 * (Ee + e)]; }      // int64: low words
    else   { s = ei[e];     d = ei[Ee + e]; }            // int32
    if ((unsigned)s < (unsigned)Nn && (unsigned)d < (unsigned)Nn) {
        int slot = atomicAdd(&cnt[d], 1);
        if (slot < CAP) bucket[(size_t)d * CAP + slot] = s;
    }
}

__global__ __launch_bounds__(256) void compute_dinv(const int* __restrict__ cnt,
                                                    float* __restrict__ dinv) {
    int i = blockIdx.x * 256 + threadIdx.x;
    if (i < Nn) dinv[i] = 1.0f / sqrtf((float)(cnt[i] + 1));  // +1 self loop
}

// ---------------- 128x128-tile fp32 GEMM: C = act(A[M,128] @ W[128,128] (+bias)) ----------------
__global__ __launch_bounds__(256) void gemm_tile(const float* __restrict__ A,
                                                 const float* __restrict__ W,
                                                 const float* __restrict__ bias,
                                                 float* __restrict__ C,
                                                 int M, int doRelu) {
    __shared__ float As[16][128];
    __shared__ float Bs[16][128];
    const int tid = threadIdx.x;
    const int tx = tid & 15;   // col group (8 cols)
    const int ty = tid >> 4;   // row group (8 rows)
    const int r0 = blockIdx.x * 128;

    float acc[8][8];
#pragma unroll
    for (int i = 0; i < 8; ++i)
#pragma unroll
        for (int j = 0; j < 8; ++j) acc[i][j] = 0.0f;

    // A staging: thread loads row (tid>>1), k-half (tid&1)*8, 8 floats
    const int la_row = tid >> 1;
    const int la_k   = (tid & 1) * 8;
    const bool la_ok = (r0 + la_row) < M;
    const float* Aptr = A + (size_t)(r0 + la_row) * D + la_k;
    // B staging: thread loads k=tid>>4, cols (tid&15)*8
    const int lb_k = tid >> 4;
    const int lb_c = (tid & 15) * 8;
    const float* Bptr = W + (size_t)lb_k * D + lb_c;

#pragma unroll 1
    for (int kb = 0; kb < D; kb += 16) {
        float4 a0 = {0, 0, 0, 0}, a1 = {0, 0, 0, 0};
        if (la_ok) {
            a0 = *(const float4*)(Aptr + kb);
            a1 = *(const float4*)(Aptr + kb + 4);
        }
        float4 b0 = *(const float4*)(Bptr + (size_t)kb * D);
        float4 b1 = *(const float4*)(Bptr + (size_t)kb * D + 4);
        __syncthreads();  // prev iteration's LDS reads done
        As[la_k + 0][la_row] = a0.x;
        As[la_k + 1][la_row] = a0.y;
        As[la_k + 2][la_row] = a0.z;
        As[la_k + 3][la_row] = a0.w;
        As[la_k + 4][la_row] = a1.x;
        As[la_k + 5][la_row] = a1.y;
        As[la_k + 6][la_row] = a1.z;
        As[la_k + 7][la_row] = a1.w;
        *(float4*)&Bs[lb_k][lb_c]     = b0;
        *(float4*)&Bs[lb_k][lb_c + 4] = b1;
        __syncthreads();
#pragma unroll
        for (int k = 0; k < 16; ++k) {
            float4 av0 = *(const float4*)&As[k][ty * 8];
            float4 av1 = *(const float4*)&As[k][ty * 8 + 4];
            float4 bv0 = *(const float4*)&Bs[k][tx * 8];
            float4 bv1 = *(const float4*)&Bs[k][tx * 8 + 4];
            float a[8] = {av0.x, av0.y, av0.z, av0.w, av1.x, av1.y, av1.z, av1.w};
            float b[8] = {bv0.x, bv0.y, bv0.z, bv0.w, bv1.x, bv1.y, bv1.z, bv1.w};
#pragma unroll
            for (int i = 0; i < 8; ++i)
#pragma unroll
                for (int j = 0; j < 8; ++j) acc[i][j] += a[i] * b[j];
        }
    }

    float bvals[8];
#pragma unroll
    for (int j = 0; j < 8; ++j) bvals[j] = bias ? bias[tx * 8 + j] : 0.0f;

#pragma unroll
    for (int i = 0; i < 8; ++i) {
        int r = r0 + ty * 8 + i;
        if (r >= M) break;
        float o[8];
#pragma unroll
        for (int j = 0; j < 8; ++j) {
            float v = acc[i][j] + bvals[j];
            o[j] = (doRelu && v < 0.0f) ? 0.0f : v;
        }
        *(float4*)(C + (size_t)r * D + tx * 8)     = make_float4(o[0], o[1], o[2], o[3]);
        *(float4*)(C + (size_t)r * D + tx * 8 + 4) = make_float4(o[4], o[5], o[6], o[7]);
    }
}

// ---------------- aggregation: hout[i] = relu( sum_{s->i} tmp[s]*dinv[s]*dinv[i] + tmp[i]*dinv[i]^2 + b ) ----
__global__ __launch_bounds__(256) void aggregate(const float* __restrict__ tmp,
                                                 const int* __restrict__ cnt,
                                                 const int* __restrict__ bucket,
                                                 const float* __restrict__ dinv,
                                                 const float* __restrict__ bias,
                                                 float* __restrict__ hout) {
    int node = (blockIdx.x * 256 + threadIdx.x) >> 6;  // one wave (64 lanes) per node
    int lane = threadIdx.x & 63;
    if (node >= Nn) return;
    const float2* t2 = (const float2*)tmp;
    float di = dinv[node];
    float2 acc = t2[(size_t)node * 64 + lane];  // self loop
    float sw = di * di;
    acc.x *= sw;
    acc.y *= sw;
    int c = cnt[node];
    if (c > CAP) c = CAP;
    const int* bk = bucket + (size_t)node * CAP;
    for (int e = 0; e < c; ++e) {
        int s = bk[e];
        float w = dinv[s] * di;
        float2 v = t2[(size_t)s * 64 + lane];
        acc.x += v.x * w;
        acc.y += v.y * w;
    }
    float2 bb = ((const float2*)bias)[lane];
    acc.x += bb.x;
    acc.y += bb.y;
    if (acc.x < 0.0f) acc.x = 0.0f;
    if (acc.y < 0.0f) acc.y = 0.0f;
    ((float2*)hout)[(size_t)node * 64 + lane] = acc;
}

// ---------------- classifier slice: out (+)= h[M,128] @ Wc[128,40] (+ b_cls when first) ---------
__global__ __launch_bounds__(256) void cls_gemm(const float* __restrict__ h,
                                                const float* __restrict__ Wc,
                                                const float* __restrict__ bias,
                                                float* __restrict__ out,
                                                int first) {
    __shared__ float Ws[D * DOUT];  // 20 KB
    const int tid = threadIdx.x;
    for (int i = tid; i < D * DOUT; i += 256) Ws[i] = Wc[i];
    __syncthreads();
    int row = blockIdx.x * 256 + tid;
    if (row >= Nn) return;

    float4 acc4[10];
    if (first) {
        const float4* b4 = (const float4*)bias;
#pragma unroll
        for (int c4 = 0; c4 < 10; ++c4) acc4[c4] = b4[c4];
    } else {
        const float4* o4 = (const float4*)(out + (size_t)row * DOUT);
#pragma unroll
        for (int c4 = 0; c4 < 10; ++c4) acc4[c4] = o4[c4];
    }

    const float4* h4 = (const float4*)(h + (size_t)row * D);
#pragma unroll 2
    for (int k4 = 0; k4 < 32; ++k4) {
        float4 hv = h4[k4];
        float hs[4] = {hv.x, hv.y, hv.z, hv.w};
        int kk = k4 * 4;
#pragma unroll
        for (int k2 = 0; k2 < 4; ++k2) {
#pragma unroll
            for (int c4 = 0; c4 < 10; ++c4) {
                float4 w = *(const float4*)&Ws[(kk + k2) * DOUT + c4 * 4];
                acc4[c4].x += hs[k2] * w.x;
                acc4[c4].y += hs[k2] * w.y;
                acc4[c4].z += hs[k2] * w.z;
                acc4[c4].w += hs[k2] * w.w;
            }
        }
    }
    float4* o4 = (float4*)(out + (size_t)row * DOUT);
#pragma unroll
    for (int c4 = 0; c4 < 10; ++c4) o4[c4] = acc4[c4];
}

// ---------------- launch ----------------
extern "C" void kernel_launch(void* const* d_in, const int* in_sizes, int n_in,
                              void* d_out, int out_size, void* d_ws, size_t ws_size,
                              hipStream_t stream) {
    const float* x       = (const float*)d_in[0];
    const int*   ei      = (const int*)d_in[1];
    const float* W_embed = (const float*)d_in[2];
    const float* b_embed = (const float*)d_in[3];
    const float* W_conv1 = (const float*)d_in[4];
    const float* b_conv1 = (const float*)d_in[5];
    const float* W_conv2 = (const float*)d_in[6];
    const float* b_conv2 = (const float*)d_in[7];
    const float* W_cls   = (const float*)d_in[8];
    const float* b_cls   = (const float*)d_in[9];
    float* out = (float*)d_out;

    // workspace carve (256B aligned)
    char* p = (char*)d_ws;
    size_t o = 0;
    auto carve = [&](size_t bytes) {
        char* r = p + o;
        o = (o + bytes + 255) & ~(size_t)255;
        return r;
    };
    int*   cnt    = (int*)carve((size_t)Nn * 4);
    int*   flag   = (int*)carve(4);
    float* dinv   = (float*)carve((size_t)Nn * 4);
    int*   bucket = (int*)carve((size_t)Nn * CAP * 4);
    float* bufA   = (float*)carve((size_t)Nn * D * 4);
    float* bufB   = (float*)carve((size_t)Nn * D * 4);
    (void)ws_size;

    hipMemsetAsync(cnt, 0, (size_t)Nn * 4, stream);
    detect_layout<<<1, 64, 0, stream>>>(ei, flag);
    build_buckets<<<(Ee + 255) / 256, 256, 0, stream>>>(ei, flag, cnt, bucket);
    compute_dinv<<<(Nn + 255) / 256, 256, 0, stream>>>(cnt, dinv);

    const int gGemm = (Nn + 127) / 128;
    const int gCls  = (Nn + 255) / 256;
    const int gAgg  = (Nn * 64) / 256;  // one wave per node

    // h0 = relu(x @ W_embed + b_embed)
    gemm_tile<<<gGemm, 256, 0, stream>>>(x, W_embed, b_embed, bufA, Nn, 1);
    // out = b_cls + h0 @ Wc[0:128]
    cls_gemm<<<gCls, 256, 0, stream>>>(bufA, W_cls + 0 * D * DOUT, b_cls, out, 1);

    // conv1: tmp = h0 @ W1 ; h1 = relu(agg(tmp) + b1)
    gemm_tile<<<gGemm, 256, 0, stream>>>(bufA, W_conv1, nullptr, bufB, Nn, 0);
    aggregate<<<gAgg, 256, 0, stream>>>(bufB, cnt, bucket, dinv, b_conv1, bufA);
    cls_gemm<<<gCls, 256, 0, stream>>>(bufA, W_cls + 1 * D * DOUT, b_cls, out, 0);

    // conv2: tmp = h1 @ W2 ; h2 = relu(agg(tmp) + b2)
    gemm_tile<<<gGemm, 256, 0, stream>>>(bufA, W_conv2, nullptr, bufB, Nn, 0);
    aggregate<<<gAgg, 256, 0, stream>>>(bufB, cnt, bucket, dinv, b_conv2, bufA);
    cls_gemm<<<gCls, 256, 0, stream>>>(bufA, W_cls + 2 * D * DOUT, b_cls, out, 0);
}

// Round 2
// 547.255 us; speedup vs baseline: 1.3406x; 1.3406x over previous
//
#include <hip/hip_runtime.h>

// ---------------- problem constants ----------------
constexpr int Nn   = 100000;   // nodes
constexpr int Ee   = 1600000;  // edges
constexpr int D    = 128;      // hidden = input dim
constexpr int DOUT = 40;       // classifier out
constexpr int CAP  = 80;       // max in-degree bucket (Poisson(16): P(deg>=80) ~ 1e-28)

typedef _Float16 f16;
typedef _Float16 f16x2 __attribute__((ext_vector_type(2)));
typedef _Float16 f16x8 __attribute__((ext_vector_type(8)));
typedef float    f32x4 __attribute__((ext_vector_type(4)));

// ---------------- edge dtype detect ----------------
__global__ void detect_layout(const int* __restrict__ ei, int* __restrict__ flag) {
    if (threadIdx.x == 0 && blockIdx.x == 0) {
        unsigned orv = 0;
        for (int j = 0; j < 256; ++j) orv |= (unsigned)ei[2 * j + 1];
        *flag = (orv == 0u) ? 1 : 0;  // 1 => int64 layout
    }
}

// ---------------- bucket build (counting) ----------------
__global__ __launch_bounds__(256) void build_buckets(const int* __restrict__ ei,
                                                     const int* __restrict__ flag,
                                                     int* __restrict__ cnt,
                                                     int* __restrict__ bucket) {
    int e = blockIdx.x * 256 + threadIdx.x;
    if (e >= Ee) return;
    int f = *flag;
    int s, d;
    if (f) { s = ei[2 * e]; d = ei[2 * (Ee + e)]; }      // int64: low words
    else   { s = ei[e];     d = ei[Ee + e]; }            // int32
    if ((unsigned)s < (unsigned)Nn && (unsigned)d < (unsigned)Nn) {
        int slot = atomicAdd(&cnt[d], 1);
        if (slot < CAP) bucket[(size_t)d * CAP + slot] = s;
    }
}

__global__ __launch_bounds__(256) void compute_dinv(const int* __restrict__ cnt,
                                                    float* __restrict__ dinv) {
    int i = blockIdx.x * 256 + threadIdx.x;
    if (i < Nn) dinv[i] = 1.0f / sqrtf((float)(cnt[i] + 1));  // +1 self loop
}

// ---------------- W transpose + fp16 convert: Wt[c][k] = W[k][c] ----------------
__global__ __launch_bounds__(256) void transpose_w(const float* __restrict__ W0,
                                                   const float* __restrict__ W1,
                                                   const float* __restrict__ W2,
                                                   f16* __restrict__ T) {
    const float* W = (blockIdx.x == 0) ? W0 : ((blockIdx.x == 1) ? W1 : W2);
    f16* Wt = T + (size_t)blockIdx.x * D * D;
    for (int i = threadIdx.x; i < D * D; i += 256) {
        int k = i >> 7, c = i & 127;
        Wt[c * D + k] = (f16)W[i];
    }
}

// ---------------- MFMA GEMM: C[M,128](f16) = act(A[M,128] @ Wt^T (+bias)) ----------------
// Wt is [col][k] (pre-transposed) so B-fragments are contiguous 16B LDS reads.
// LDS XOR-swizzle (G4): byte_in_row ^= (row&7)<<4 — breaks the 256B-stride bank conflict.
template <int AFP32>
__global__ __launch_bounds__(256) void gemm_mfma(const void* __restrict__ Ain,
                                                 const f16* __restrict__ Wt,
                                                 const float* __restrict__ bias,
                                                 f16* __restrict__ C,
                                                 int M, int doRelu) {
    __shared__ f16 Asw[128 * 128];  // 32 KB
    __shared__ f16 Bsw[128 * 128];  // 32 KB
    const int tid = threadIdx.x;
    const int r0 = blockIdx.x * 128;

    // --- stage B (Wt fp16): thread t -> row t>>1, half-row (t&1)*128 bytes ---
    {
        int row = tid >> 1, half = (tid & 1) * 128;
#pragma unroll
        for (int i = 0; i < 8; ++i) {
            int bir = half + i * 16;
            uint4 v = *(const uint4*)((const char*)Wt + (size_t)row * 256 + bir);
            *(uint4*)((char*)Bsw + row * 256 + (bir ^ ((row & 7) << 4))) = v;
        }
    }
    // --- stage A ---
    if (AFP32) {
        const float* A = (const float*)Ain;
        int row = tid >> 1, gr = r0 + row, half = tid & 1;
#pragma unroll
        for (int i = 0; i < 8; ++i) {
            float4 f0 = {0, 0, 0, 0}, f1 = {0, 0, 0, 0};
            if (gr < M) {
                const float* p = A + (size_t)gr * 128 + half * 64 + i * 8;
                f0 = *(const float4*)p;
                f1 = *(const float4*)(p + 4);
            }
            f16x8 h;
            h[0] = (f16)f0.x; h[1] = (f16)f0.y; h[2] = (f16)f0.z; h[3] = (f16)f0.w;
            h[4] = (f16)f1.x; h[5] = (f16)f1.y; h[6] = (f16)f1.z; h[7] = (f16)f1.w;
            int bir = half * 128 + i * 16;
            *(f16x8*)((char*)Asw + row * 256 + (bir ^ ((row & 7) << 4))) = h;
        }
    } else {
        const f16* A = (const f16*)Ain;
        int row = tid >> 1, gr = r0 + row, half = (tid & 1) * 128;
#pragma unroll
        for (int i = 0; i < 8; ++i) {
            uint4 v = {0, 0, 0, 0};
            int bir = half + i * 16;
            if (gr < M) v = *(const uint4*)((const char*)A + (size_t)gr * 256 + bir);
            *(uint4*)((char*)Asw + row * 256 + (bir ^ ((row & 7) << 4))) = v;
        }
    }
    __syncthreads();

    const int lane = tid & 63;
    const int w    = tid >> 6;
    const int wr   = w * 32;  // wave's 32-row block

    f32x4 acc[2][8];
#pragma unroll
    for (int mf = 0; mf < 2; ++mf)
#pragma unroll
        for (int nf = 0; nf < 8; ++nf) acc[mf][nf] = (f32x4){0, 0, 0, 0};

#pragma unroll
    for (int kk = 0; kk < 4; ++kk) {
        const int kb = kk * 64;  // byte offset of K-chunk (32 halfs)
        f16x8 a[2], b[8];
#pragma unroll
        for (int mf = 0; mf < 2; ++mf) {
            int row = wr + mf * 16 + (lane & 15);
            int bir = kb + (lane >> 4) * 16;
            a[mf] = *(const f16x8*)((const char*)Asw + row * 256 + (bir ^ ((row & 7) << 4)));
        }
#pragma unroll
        for (int nf = 0; nf < 8; ++nf) {
            int col = nf * 16 + (lane & 15);
            int bir = kb + (lane >> 4) * 16;
            b[nf] = *(const f16x8*)((const char*)Bsw + col * 256 + (bir ^ ((col & 7) << 4)));
        }
#pragma unroll
        for (int mf = 0; mf < 2; ++mf)
#pragma unroll
            for (int nf = 0; nf < 8; ++nf)
                acc[mf][nf] = __builtin_amdgcn_mfma_f32_16x16x32_f16(a[mf], b[nf], acc[mf][nf], 0, 0, 0);
    }

    // --- epilogue: bias + relu + fp16 store. C/D layout: col=lane&15, row=(lane>>4)*4+i ---
    float bv[8];
#pragma unroll
    for (int nf = 0; nf < 8; ++nf) bv[nf] = bias ? bias[nf * 16 + (lane & 15)] : 0.0f;
#pragma unroll
    for (int mf = 0; mf < 2; ++mf) {
#pragma unroll
        for (int i = 0; i < 4; ++i) {
            int row = r0 + wr + mf * 16 + (lane >> 4) * 4 + i;
            if (row < M) {
#pragma unroll
                for (int nf = 0; nf < 8; ++nf) {
                    float v = acc[mf][nf][i] + bv[nf];
                    if (doRelu && v < 0.0f) v = 0.0f;
                    C[(size_t)row * 128 + nf * 16 + (lane & 15)] = (f16)v;
                }
            }
        }
    }
}

// ---------------- aggregation (fp16 rows, 8-deep gather pipeline) ----------------
// hout[i] = relu( sum_{s->i} tmp[s]*dinv[s]*dinv[i] + tmp[i]*dinv[i]^2 + b )
__global__ __launch_bounds__(256) void aggregate16(const f16* __restrict__ tmp,
                                                   const int* __restrict__ cnt,
                                                   const int* __restrict__ bucket,
                                                   const float* __restrict__ dinv,
                                                   const float* __restrict__ bias,
                                                   f16* __restrict__ hout) {
    int node = (blockIdx.x * 256 + threadIdx.x) >> 6;  // one wave per node
    int lane = threadIdx.x & 63;
    if (node >= Nn) return;
    const f16x2* t2 = (const f16x2*)tmp;

    float di = dinv[node];
    f16x2 sv = t2[(size_t)node * 64 + lane];  // self loop
    float sw = di * di;
    float ax = (float)sv[0] * sw;
    float ay = (float)sv[1] * sw;

    int c = cnt[node];
    if (c > CAP) c = CAP;
    const int* bk = bucket + (size_t)node * CAP;

    for (int e = 0; e < c; e += 8) {
        // 8 slot ids (32B, aligned: CAP*4=320 and e%8==0); over-read past c is
        // clamped + zero-weighted below, stays inside ws.
        int4 ia = *(const int4*)(bk + e);
        int4 ib = *(const int4*)(bk + e + 4);
        int s[8] = {ia.x, ia.y, ia.z, ia.w, ib.x, ib.y, ib.z, ib.w};
        f16x2 v[8];
        float w[8];
#pragma unroll
        for (int k = 0; k < 8; ++k) {
            int ss = ((unsigned)s[k] < (unsigned)Nn) ? s[k] : 0;
            v[k] = t2[(size_t)ss * 64 + lane];                    // 8 gathers in flight
            w[k] = (e + k < c) ? dinv[ss] * di : 0.0f;
        }
#pragma unroll
        for (int k = 0; k < 8; ++k) {
            ax += (float)v[k][0] * w[k];
            ay += (float)v[k][1] * w[k];
        }
    }

    float2 bb = ((const float2*)bias)[lane];
    ax += bb.x;
    ay += bb.y;
    if (ax < 0.0f) ax = 0.0f;
    if (ay < 0.0f) ay = 0.0f;
    f16x2 o;
    o[0] = (f16)ax;
    o[1] = (f16)ay;
    ((f16x2*)hout)[(size_t)node * 64 + lane] = o;
}

// ---------------- fused classifier: out = b + [h0,h1,h2] @ W_cls ----------------
__global__ __launch_bounds__(256) void cls_fused(const f16* __restrict__ h0,
                                                 const f16* __restrict__ h1,
                                                 const f16* __restrict__ h2,
                                                 const float* __restrict__ Wc,
                                                 const float* __restrict__ bc,
                                                 float* __restrict__ out) {
    __shared__ float Ws[384 * DOUT];  // 61.4 KB
    for (int i = threadIdx.x; i < 384 * DOUT; i += 256) Ws[i] = Wc[i];
    __syncthreads();
    int row = blockIdx.x * 256 + threadIdx.x;
    if (row >= Nn) return;

    float4 acc4[10];
    const float4* b4 = (const float4*)bc;
#pragma unroll
    for (int c4 = 0; c4 < 10; ++c4) acc4[c4] = b4[c4];

#pragma unroll
    for (int part = 0; part < 3; ++part) {
        const f16* hp = (part == 0) ? h0 : ((part == 1) ? h1 : h2);
        const f16x8* hr = (const f16x8*)(hp + (size_t)row * 128);
#pragma unroll 4
        for (int k8 = 0; k8 < 16; ++k8) {
            f16x8 hv = hr[k8];
#pragma unroll
            for (int j = 0; j < 8; ++j) {
                float a = (float)hv[j];
                const float4* wrow = (const float4*)&Ws[(part * 128 + k8 * 8 + j) * DOUT];
#pragma unroll
                for (int c4 = 0; c4 < 10; ++c4) {
                    float4 wv = wrow[c4];
                    acc4[c4].x += a * wv.x;
                    acc4[c4].y += a * wv.y;
                    acc4[c4].z += a * wv.z;
                    acc4[c4].w += a * wv.w;
                }
            }
        }
    }
    float4* o4 = (float4*)(out + (size_t)row * DOUT);
#pragma unroll
    for (int c4 = 0; c4 < 10; ++c4) o4[c4] = acc4[c4];
}

// ---------------- launch ----------------
extern "C" void kernel_launch(void* const* d_in, const int* in_sizes, int n_in,
                              void* d_out, int out_size, void* d_ws, size_t ws_size,
                              hipStream_t stream) {
    const float* x       = (const float*)d_in[0];
    const int*   ei      = (const int*)d_in[1];
    const float* W_embed = (const float*)d_in[2];
    const float* b_embed = (const float*)d_in[3];
    const float* W_conv1 = (const float*)d_in[4];
    const float* b_conv1 = (const float*)d_in[5];
    const float* W_conv2 = (const float*)d_in[6];
    const float* b_conv2 = (const float*)d_in[7];
    const float* W_cls   = (const float*)d_in[8];
    const float* b_cls   = (const float*)d_in[9];
    float* out = (float*)d_out;

    // workspace carve (256B aligned)
    char* p = (char*)d_ws;
    size_t o = 0;
    auto carve = [&](size_t bytes) {
        char* r = p + o;
        o = (o + bytes + 255) & ~(size_t)255;
        return r;
    };
    int*   cnt    = (int*)carve((size_t)Nn * 4);
    int*   flag   = (int*)carve(4);
    float* dinv   = (float*)carve((size_t)Nn * 4);
    int*   bucket = (int*)carve((size_t)Nn * CAP * 4);
    f16*   WtAll  = (f16*)carve((size_t)3 * D * D * 2);
    f16*   h0     = (f16*)carve((size_t)Nn * D * 2);
    f16*   h1     = (f16*)carve((size_t)Nn * D * 2);
    f16*   h2     = (f16*)carve((size_t)Nn * D * 2);
    f16*   tmp    = (f16*)carve((size_t)Nn * D * 2);
    (void)ws_size;

    hipMemsetAsync(cnt, 0, (size_t)Nn * 4, stream);
    detect_layout<<<1, 64, 0, stream>>>(ei, flag);
    build_buckets<<<(Ee + 255) / 256, 256, 0, stream>>>(ei, flag, cnt, bucket);
    compute_dinv<<<(Nn + 255) / 256, 256, 0, stream>>>(cnt, dinv);
    transpose_w<<<3, 256, 0, stream>>>(W_embed, W_conv1, W_conv2, WtAll);

    const int gGemm = (Nn + 127) / 128;
    const int gCls  = (Nn + 255) / 256;
    const int gAgg  = (Nn * 64) / 256;

    // h0 = relu(x @ W_embed + b_embed)
    gemm_mfma<1><<<gGemm, 256, 0, stream>>>(x, WtAll, b_embed, h0, Nn, 1);
    // conv1
    gemm_mfma<0><<<gGemm, 256, 0, stream>>>(h0, WtAll + D * D, nullptr, tmp, Nn, 0);
    aggregate16<<<gAgg, 256, 0, stream>>>(tmp, cnt, bucket, dinv, b_conv1, h1);
    // conv2
    gemm_mfma<0><<<gGemm, 256, 0, stream>>>(h1, WtAll + 2 * D * D, nullptr, tmp, Nn, 0);
    aggregate16<<<gAgg, 256, 0, stream>>>(tmp, cnt, bucket, dinv, b_conv2, h2);
    // classifier (single fused dispatch)
    cls_fused<<<gCls, 256, 0, stream>>>(h0, h1, h2, W_cls, b_cls, out);
}

// Round 3
// 378.039 us; speedup vs baseline: 1.9407x; 1.4476x over previous
//
#include <hip/hip_runtime.h>

// ---------------- problem constants ----------------
constexpr int Nn   = 100000;   // nodes
constexpr int Ee   = 1600000;  // edges
constexpr int D    = 128;      // hidden = input dim
constexpr int DOUT = 40;       // classifier out

// binned-sort parameters
constexpr int BINSH  = 8;                          // 256 nodes per bin
constexpr int BINSZ  = 1 << BINSH;
constexpr int BINS   = (Nn + BINSZ - 1) / BINSZ;   // 391
constexpr int CHUNK  = 8192;                       // edges per scatter block
constexpr int NCHUNK = (Ee + CHUNK - 1) / CHUNK;   // 196
constexpr int SEGCAP = 5376;                       // max edges/bin (mean 4092, +20 sigma)

typedef _Float16 f16;
typedef _Float16 f16x2 __attribute__((ext_vector_type(2)));
typedef _Float16 f16x8 __attribute__((ext_vector_type(8)));
typedef float    f32x4 __attribute__((ext_vector_type(4)));

// ---------------- edge dtype detect ----------------
__global__ void detect_layout(const int* __restrict__ ei, int* __restrict__ flag) {
    if (threadIdx.x == 0 && blockIdx.x == 0) {
        unsigned orv = 0;
        for (int j = 0; j < 256; ++j) orv |= (unsigned)ei[2 * j + 1];
        *flag = (orv == 0u) ? 1 : 0;  // 1 => int64 layout
    }
}

__device__ inline void load_edge(const int* __restrict__ ei, int f, int e, int& s, int& d) {
    if (f) {  // int64: read 8B, use low word
        s = ((const int2*)ei)[e].x;
        d = ((const int2*)ei)[Ee + e].x;
    } else {
        s = ei[e];
        d = ei[Ee + e];
    }
}

// inclusive Hillis-Steele scan of n2 (<=512) ints with 256 threads, double-buffered.
// pa pre-filled (zero-padded to n2), synced. Returns buffer holding the result.
__device__ inline int* scan_incl(int* pa, int* pb, int n2, int tid) {
    for (int off = 1; off < n2; off <<= 1) {
        for (int i = tid; i < n2; i += 256) pb[i] = pa[i] + ((i >= off) ? pa[i - off] : 0);
        __syncthreads();
        int* t = pa; pa = pb; pb = t;
    }
    return pa;
}

// ---------------- P1: per-bin edge histogram ----------------
__global__ __launch_bounds__(256) void bin_hist(const int* __restrict__ ei,
                                                const int* __restrict__ flag,
                                                int* __restrict__ binCnt) {
    __shared__ int h[BINS];
    for (int i = threadIdx.x; i < BINS; i += 256) h[i] = 0;
    __syncthreads();
    int f = *flag;
    for (int e = blockIdx.x * 256 + threadIdx.x; e < Ee; e += gridDim.x * 256) {
        int s, d;
        load_edge(ei, f, e, s, d);
        if ((unsigned)s < (unsigned)Nn && (unsigned)d < (unsigned)Nn)
            atomicAdd(&h[d >> BINSH], 1);
    }
    __syncthreads();
    for (int i = threadIdx.x; i < BINS; i += 256)
        if (h[i]) atomicAdd(&binCnt[i], h[i]);
}

// ---------------- P2: scan bins -> offsets, init cursors, pad CSR ----------------
__global__ __launch_bounds__(512) void bin_scan(const int* __restrict__ binCnt,
                                                int* __restrict__ binOff,
                                                int* __restrict__ binCursor,
                                                int* __restrict__ rowPtr,
                                                int* __restrict__ sortedSrc) {
    __shared__ int a[512];
    int t = threadIdx.x;
    int v = (t < BINS) ? binCnt[t] : 0;
    a[t] = v;
    __syncthreads();
    for (int off = 1; off < 512; off <<= 1) {
        int x = a[t] + ((t >= off) ? a[t - off] : 0);
        __syncthreads();
        a[t] = x;
        __syncthreads();
    }
    if (t < BINS) { binOff[t] = a[t] - v; binCursor[t] = a[t] - v; }
    int E = a[BINS - 1];
    if (t == 0) { binOff[BINS] = E; rowPtr[Nn] = E; }
    if (t < 8) sortedSrc[E + t] = 0;  // pad for unconditional 8-wide reads
}

// ---------------- P3: binning scatter (coalesced run writes) ----------------
__global__ __launch_bounds__(256) void bin_scatter(const int* __restrict__ ei,
                                                   const int* __restrict__ flag,
                                                   int* __restrict__ binCursor,
                                                   unsigned* __restrict__ arena) {
    __shared__ unsigned srec[CHUNK];                       // 32 KB
    __shared__ int bcnt[BINS], bpfx[BINS], bfill[BINS], gbase[BINS];
    __shared__ int pA[512], pB[512];
    const int tid = threadIdx.x;
    const int e0 = blockIdx.x * CHUNK;
    const int n = min(CHUNK, Ee - e0);
    const int f = *flag;

    for (int i = tid; i < BINS; i += 256) { bcnt[i] = 0; bfill[i] = 0; }
    __syncthreads();
    for (int i = tid; i < n; i += 256) {
        int s, d;
        load_edge(ei, f, e0 + i, s, d);
        if ((unsigned)s < (unsigned)Nn && (unsigned)d < (unsigned)Nn)
            atomicAdd(&bcnt[d >> BINSH], 1);
    }
    __syncthreads();
    for (int i = tid; i < 512; i += 256) pA[i] = (i < BINS) ? bcnt[i] : 0;
    __syncthreads();
    int* incl = scan_incl(pA, pB, 512, tid);
    for (int i = tid; i < BINS; i += 256) {
        bpfx[i] = incl[i] - bcnt[i];
        gbase[i] = bcnt[i] ? atomicAdd(&binCursor[i], bcnt[i]) : 0;
    }
    __syncthreads();
    for (int i = tid; i < n; i += 256) {
        int s, d;
        load_edge(ei, f, e0 + i, s, d);
        if ((unsigned)s < (unsigned)Nn && (unsigned)d < (unsigned)Nn) {
            int bin = d >> BINSH;
            int lp = atomicAdd(&bfill[bin], 1);
            srec[bpfx[bin] + lp] = ((unsigned)(d & (BINSZ - 1)) << 17) | (unsigned)s;
        }
    }
    __syncthreads();
    // coalesced per-bin run copy: wave w handles bins w, w+4, ...
    const int wid = tid >> 6, lane = tid & 63;
    for (int bin = wid; bin < BINS; bin += 4) {
        int cnt = bcnt[bin], off = bpfx[bin], gb = gbase[bin];
        for (int j = lane; j < cnt; j += 64) arena[gb + j] = srec[off + j];
    }
}

// ---------------- P4: per-bin finalize -> CSR + rowPtr + dinv ----------------
__global__ __launch_bounds__(256) void bin_finalize(const int* __restrict__ binOff,
                                                    const unsigned* __restrict__ arena,
                                                    int* __restrict__ rowPtr,
                                                    float* __restrict__ dinv,
                                                    int* __restrict__ sortedSrc) {
    __shared__ unsigned seg[SEGCAP];   // 21 KB
    __shared__ int ssrc[SEGCAP];       // 21 KB
    __shared__ int cnt[BINSZ], fill[BINSZ], pA[BINSZ], pB[BINSZ];
    const int tid = threadIdx.x;
    const int b = blockIdx.x;
    const int base = binOff[b];
    int len = binOff[b + 1] - base;
    if (len > SEGCAP) len = SEGCAP;

    for (int i = tid; i < len; i += 256) seg[i] = arena[base + i];
    for (int i = tid; i < BINSZ; i += 256) { cnt[i] = 0; fill[i] = 0; }
    __syncthreads();
    for (int i = tid; i < len; i += 256) atomicAdd(&cnt[seg[i] >> 17], 1);
    __syncthreads();
    for (int i = tid; i < BINSZ; i += 256) pA[i] = cnt[i];
    __syncthreads();
    int* incl = scan_incl(pA, pB, BINSZ, tid);

    const int node0 = b * BINSZ;
    for (int t = tid; t < BINSZ; t += 256) {
        int node = node0 + t;
        if (node < Nn) {
            rowPtr[node] = base + incl[t] - cnt[t];
            dinv[node] = rsqrtf((float)(cnt[t] + 1));  // +1 self loop
        }
    }
    __syncthreads();
    for (int i = tid; i < len; i += 256) {
        unsigned r = seg[i];
        int dl = r >> 17, s = (int)(r & 0x1FFFFu);
        int p = atomicAdd(&fill[dl], 1);
        ssrc[incl[dl] - cnt[dl] + p] = s;
    }
    __syncthreads();
    for (int i = tid; i < len; i += 256) sortedSrc[base + i] = ssrc[i];
}

// ---------------- W transpose + fp16 convert: Wt[c][k] = W[k][c] ----------------
__global__ __launch_bounds__(256) void transpose_w(const float* __restrict__ W0,
                                                   const float* __restrict__ W1,
                                                   const float* __restrict__ W2,
                                                   f16* __restrict__ T) {
    const float* W = (blockIdx.x == 0) ? W0 : ((blockIdx.x == 1) ? W1 : W2);
    f16* Wt = T + (size_t)blockIdx.x * D * D;
    for (int i = threadIdx.x; i < D * D; i += 256) {
        int k = i >> 7, c = i & 127;
        Wt[c * D + k] = (f16)W[i];
    }
}

// ---------------- MFMA GEMM: C[M,128](f16) = act(A[M,128] @ Wt^T (+bias)) * scale ----------------
template <int AFP32>
__global__ __launch_bounds__(256) void gemm_mfma(const void* __restrict__ Ain,
                                                 const f16* __restrict__ Wt,
                                                 const float* __restrict__ bias,
                                                 const float* __restrict__ scale,
                                                 f16* __restrict__ C,
                                                 int M, int doRelu) {
    __shared__ f16 Asw[128 * 128];  // 32 KB
    __shared__ f16 Bsw[128 * 128];  // 32 KB
    const int tid = threadIdx.x;
    const int r0 = blockIdx.x * 128;

    {   // stage B
        int row = tid >> 1, half = (tid & 1) * 128;
#pragma unroll
        for (int i = 0; i < 8; ++i) {
            int bir = half + i * 16;
            uint4 v = *(const uint4*)((const char*)Wt + (size_t)row * 256 + bir);
            *(uint4*)((char*)Bsw + row * 256 + (bir ^ ((row & 7) << 4))) = v;
        }
    }
    if (AFP32) {
        const float* A = (const float*)Ain;
        int row = tid >> 1, gr = r0 + row, half = tid & 1;
#pragma unroll
        for (int i = 0; i < 8; ++i) {
            float4 f0 = {0, 0, 0, 0}, f1 = {0, 0, 0, 0};
            if (gr < M) {
                const float* p = A + (size_t)gr * 128 + half * 64 + i * 8;
                f0 = *(const float4*)p;
                f1 = *(const float4*)(p + 4);
            }
            f16x8 h;
            h[0] = (f16)f0.x; h[1] = (f16)f0.y; h[2] = (f16)f0.z; h[3] = (f16)f0.w;
            h[4] = (f16)f1.x; h[5] = (f16)f1.y; h[6] = (f16)f1.z; h[7] = (f16)f1.w;
            int bir = half * 128 + i * 16;
            *(f16x8*)((char*)Asw + row * 256 + (bir ^ ((row & 7) << 4))) = h;
        }
    } else {
        const f16* A = (const f16*)Ain;
        int row = tid >> 1, gr = r0 + row, half = (tid & 1) * 128;
#pragma unroll
        for (int i = 0; i < 8; ++i) {
            uint4 v = {0, 0, 0, 0};
            int bir = half + i * 16;
            if (gr < M) v = *(const uint4*)((const char*)A + (size_t)gr * 256 + bir);
            *(uint4*)((char*)Asw + row * 256 + (bir ^ ((row & 7) << 4))) = v;
        }
    }
    __syncthreads();

    const int lane = tid & 63;
    const int w    = tid >> 6;
    const int wr   = w * 32;

    f32x4 acc[2][8];
#pragma unroll
    for (int mf = 0; mf < 2; ++mf)
#pragma unroll
        for (int nf = 0; nf < 8; ++nf) acc[mf][nf] = (f32x4){0, 0, 0, 0};

#pragma unroll
    for (int kk = 0; kk < 4; ++kk) {
        const int kb = kk * 64;
        f16x8 a[2], b[8];
#pragma unroll
        for (int mf = 0; mf < 2; ++mf) {
            int row = wr + mf * 16 + (lane & 15);
            int bir = kb + (lane >> 4) * 16;
            a[mf] = *(const f16x8*)((const char*)Asw + row * 256 + (bir ^ ((row & 7) << 4)));
        }
#pragma unroll
        for (int nf = 0; nf < 8; ++nf) {
            int col = nf * 16 + (lane & 15);
            int bir = kb + (lane >> 4) * 16;
            b[nf] = *(const f16x8*)((const char*)Bsw + col * 256 + (bir ^ ((col & 7) << 4)));
        }
#pragma unroll
        for (int mf = 0; mf < 2; ++mf)
#pragma unroll
            for (int nf = 0; nf < 8; ++nf)
                acc[mf][nf] = __builtin_amdgcn_mfma_f32_16x16x32_f16(a[mf], b[nf], acc[mf][nf], 0, 0, 0);
    }

    float bv[8];
#pragma unroll
    for (int nf = 0; nf < 8; ++nf) bv[nf] = bias ? bias[nf * 16 + (lane & 15)] : 0.0f;
#pragma unroll
    for (int mf = 0; mf < 2; ++mf) {
#pragma unroll
        for (int i = 0; i < 4; ++i) {
            int row = r0 + wr + mf * 16 + (lane >> 4) * 4 + i;
            if (row < M) {
                float sc = scale ? scale[row] : 1.0f;
#pragma unroll
                for (int nf = 0; nf < 8; ++nf) {
                    float v = acc[mf][nf][i] + bv[nf];
                    if (doRelu && v < 0.0f) v = 0.0f;
                    C[(size_t)row * 128 + nf * 16 + (lane & 15)] = (f16)(v * sc);
                }
            }
        }
    }
}

// ---------------- CSR aggregation (tmp pre-scaled by dinv[src]) ----------------
// hout[i] = relu( dinv[i] * ( sum_{s in N(i)} tmp[s] + tmp[i] ) + b )
__global__ __launch_bounds__(256) void aggregate_csr(const f16* __restrict__ tmp,
                                                     const int* __restrict__ rowPtr,
                                                     const int* __restrict__ sortedSrc,
                                                     const float* __restrict__ dinv,
                                                     const float* __restrict__ bias,
                                                     f16* __restrict__ hout) {
    int node = (blockIdx.x * 256 + threadIdx.x) >> 6;  // one wave per node
    int lane = threadIdx.x & 63;
    if (node >= Nn) return;
    const f16x2* t2 = (const f16x2*)tmp;

    int base = rowPtr[node];
    int c = rowPtr[node + 1] - base;
    float di = dinv[node];

    f16x2 sv = t2[(size_t)node * 64 + lane];  // self (already *dinv[node])
    float ax = (float)sv[0];
    float ay = (float)sv[1];

    for (int e = 0; e < c; e += 8) {
        int s[8];
        f16x2 v[8];
#pragma unroll
        for (int k = 0; k < 8; ++k) {
            int raw = sortedSrc[base + e + k];       // safe: 8-padded
            s[k] = (e + k < c) ? raw : 0;            // masked -> hot row 0
        }
#pragma unroll
        for (int k = 0; k < 8; ++k) v[k] = t2[(size_t)s[k] * 64 + lane];  // 8 gathers in flight
#pragma unroll
        for (int k = 0; k < 8; ++k) {
            bool m = (e + k) < c;
            ax += m ? (float)v[k][0] : 0.0f;
            ay += m ? (float)v[k][1] : 0.0f;
        }
    }

    float2 bb = ((const float2*)bias)[lane];
    ax = di * ax + bb.x;
    ay = di * ay + bb.y;
    if (ax < 0.0f) ax = 0.0f;
    if (ay < 0.0f) ay = 0.0f;
    f16x2 o;
    o[0] = (f16)ax;
    o[1] = (f16)ay;
    ((f16x2*)hout)[(size_t)node * 64 + lane] = o;
}

// ---------------- fused classifier: out = b + [h0,h1,h2] @ W_cls ----------------
__global__ __launch_bounds__(256) void cls_fused(const f16* __restrict__ h0,
                                                 const f16* __restrict__ h1,
                                                 const f16* __restrict__ h2,
                                                 const float* __restrict__ Wc,
                                                 const float* __restrict__ bc,
                                                 float* __restrict__ out) {
    __shared__ float Ws[384 * DOUT];  // 61.4 KB
    for (int i = threadIdx.x; i < 384 * DOUT; i += 256) Ws[i] = Wc[i];
    __syncthreads();
    int row = blockIdx.x * 256 + threadIdx.x;
    if (row >= Nn) return;

    float4 acc4[10];
    const float4* b4 = (const float4*)bc;
#pragma unroll
    for (int c4 = 0; c4 < 10; ++c4) acc4[c4] = b4[c4];

#pragma unroll
    for (int part = 0; part < 3; ++part) {
        const f16* hp = (part == 0) ? h0 : ((part == 1) ? h1 : h2);
        const f16x8* hr = (const f16x8*)(hp + (size_t)row * 128);
#pragma unroll 4
        for (int k8 = 0; k8 < 16; ++k8) {
            f16x8 hv = hr[k8];
#pragma unroll
            for (int j = 0; j < 8; ++j) {
                float a = (float)hv[j];
                const float4* wrow = (const float4*)&Ws[(part * 128 + k8 * 8 + j) * DOUT];
#pragma unroll
                for (int c4 = 0; c4 < 10; ++c4) {
                    float4 wv = wrow[c4];
                    acc4[c4].x += a * wv.x;
                    acc4[c4].y += a * wv.y;
                    acc4[c4].z += a * wv.z;
                    acc4[c4].w += a * wv.w;
                }
            }
        }
    }
    float4* o4 = (float4*)(out + (size_t)row * DOUT);
#pragma unroll
    for (int c4 = 0; c4 < 10; ++c4) o4[c4] = acc4[c4];
}

// ---------------- launch ----------------
extern "C" void kernel_launch(void* const* d_in, const int* in_sizes, int n_in,
                              void* d_out, int out_size, void* d_ws, size_t ws_size,
                              hipStream_t stream) {
    const float* x       = (const float*)d_in[0];
    const int*   ei      = (const int*)d_in[1];
    const float* W_embed = (const float*)d_in[2];
    const float* b_embed = (const float*)d_in[3];
    const float* W_conv1 = (const float*)d_in[4];
    const float* b_conv1 = (const float*)d_in[5];
    const float* W_conv2 = (const float*)d_in[6];
    const float* b_conv2 = (const float*)d_in[7];
    const float* W_cls   = (const float*)d_in[8];
    const float* b_cls   = (const float*)d_in[9];
    float* out = (float*)d_out;

    char* p = (char*)d_ws;
    size_t o = 0;
    auto carve = [&](size_t bytes) {
        char* r = p + o;
        o = (o + bytes + 255) & ~(size_t)255;
        return r;
    };
    int*      binCnt    = (int*)carve((size_t)BINS * 4);
    int*      binOff    = (int*)carve((size_t)(BINS + 1) * 4);
    int*      binCursor = (int*)carve((size_t)BINS * 4);
    unsigned* arena     = (unsigned*)carve((size_t)Ee * 4);
    int*      rowPtr    = (int*)carve((size_t)(Nn + 1) * 4);
    int*      sortedSrc = (int*)carve((size_t)(Ee + 8) * 4);
    float*    dinv      = (float*)carve((size_t)Nn * 4);
    int*      flag      = (int*)carve(4);
    f16*      WtAll     = (f16*)carve((size_t)3 * D * D * 2);
    f16*      h0        = (f16*)carve((size_t)Nn * D * 2);
    f16*      h1        = (f16*)carve((size_t)Nn * D * 2);
    f16*      h2        = (f16*)carve((size_t)Nn * D * 2);
    f16*      tmp       = (f16*)carve((size_t)Nn * D * 2);
    (void)ws_size;

    hipMemsetAsync(binCnt, 0, (size_t)BINS * 4, stream);
    detect_layout<<<1, 64, 0, stream>>>(ei, flag);
    bin_hist<<<512, 256, 0, stream>>>(ei, flag, binCnt);
    bin_scan<<<1, 512, 0, stream>>>(binCnt, binOff, binCursor, rowPtr, sortedSrc);
    bin_scatter<<<NCHUNK, 256, 0, stream>>>(ei, flag, binCursor, arena);
    bin_finalize<<<BINS, 256, 0, stream>>>(binOff, arena, rowPtr, dinv, sortedSrc);
    transpose_w<<<3, 256, 0, stream>>>(W_embed, W_conv1, W_conv2, WtAll);

    const int gGemm = (Nn + 127) / 128;
    const int gCls  = (Nn + 255) / 256;
    const int gAgg  = (Nn * 64) / 256;

    // h0 = relu(x @ W_embed + b_embed)
    gemm_mfma<1><<<gGemm, 256, 0, stream>>>(x, WtAll, b_embed, nullptr, h0, Nn, 1);
    // conv1: tmp = (h0 @ W1) * dinv ; h1 = relu(dinv*(agg+self) + b1)
    gemm_mfma<0><<<gGemm, 256, 0, stream>>>(h0, WtAll + D * D, nullptr, dinv, tmp, Nn, 0);
    aggregate_csr<<<gAgg, 256, 0, stream>>>(tmp, rowPtr, sortedSrc, dinv, b_conv1, h1);
    // conv2
    gemm_mfma<0><<<gGemm, 256, 0, stream>>>(h1, WtAll + 2 * D * D, nullptr, dinv, tmp, Nn, 0);
    aggregate_csr<<<gAgg, 256, 0, stream>>>(tmp, rowPtr, sortedSrc, dinv, b_conv2, h2);
    // classifier
    cls_fused<<<gCls, 256, 0, stream>>>(h0, h1, h2, W_cls, b_cls, out);
}

// Round 4
// 325.707 us; speedup vs baseline: 2.2525x; 1.1607x over previous
//
#include <hip/hip_runtime.h>

// ---------------- problem constants ----------------
constexpr int Nn   = 100000;   // nodes
constexpr int Ee   = 1600000;  // edges
constexpr int D    = 128;      // hidden = input dim
constexpr int DOUT = 40;       // classifier out
constexpr int DCAT = 384;      // 3*D concat width
constexpr int CPAD = 48;       // DOUT padded to 3x16 MFMA col tiles
constexpr int WS   = 392;      // Wct row stride (halfs): 392*2B=784B -> 2-way LDS conflict only

// binned-sort parameters
constexpr int BINSH  = 8;                          // 256 nodes per bin
constexpr int BINSZ  = 1 << BINSH;
constexpr int BINS   = (Nn + BINSZ - 1) / BINSZ;   // 391
constexpr int CHUNK  = 8192;                       // edges per scatter block
constexpr int NCHUNK = (Ee + CHUNK - 1) / CHUNK;   // 196
constexpr int SEGCAP = 5376;                       // max edges/bin (mean 4092, +20 sigma)

typedef _Float16 f16;
typedef _Float16 f16x2 __attribute__((ext_vector_type(2)));
typedef _Float16 f16x8 __attribute__((ext_vector_type(8)));
typedef float    f32x4 __attribute__((ext_vector_type(4)));

// ---------------- edge dtype detect ----------------
__global__ void detect_layout(const int* __restrict__ ei, int* __restrict__ flag) {
    if (threadIdx.x == 0 && blockIdx.x == 0) {
        unsigned orv = 0;
        for (int j = 0; j < 256; ++j) orv |= (unsigned)ei[2 * j + 1];
        *flag = (orv == 0u) ? 1 : 0;  // 1 => int64 layout
    }
}

__device__ inline void load_edge(const int* __restrict__ ei, int f, int e, int& s, int& d) {
    if (f) {  // int64: read 8B, use low word
        s = ((const int2*)ei)[e].x;
        d = ((const int2*)ei)[Ee + e].x;
    } else {
        s = ei[e];
        d = ei[Ee + e];
    }
}

// inclusive Hillis-Steele scan of n2 (<=512) ints with 256 threads, double-buffered.
__device__ inline int* scan_incl(int* pa, int* pb, int n2, int tid) {
    for (int off = 1; off < n2; off <<= 1) {
        for (int i = tid; i < n2; i += 256) pb[i] = pa[i] + ((i >= off) ? pa[i - off] : 0);
        __syncthreads();
        int* t = pa; pa = pb; pb = t;
    }
    return pa;
}

// ---------------- P1: per-bin edge histogram ----------------
__global__ __launch_bounds__(256) void bin_hist(const int* __restrict__ ei,
                                                const int* __restrict__ flag,
                                                int* __restrict__ binCnt) {
    __shared__ int h[BINS];
    for (int i = threadIdx.x; i < BINS; i += 256) h[i] = 0;
    __syncthreads();
    int f = *flag;
    for (int e = blockIdx.x * 256 + threadIdx.x; e < Ee; e += gridDim.x * 256) {
        int s, d;
        load_edge(ei, f, e, s, d);
        if ((unsigned)s < (unsigned)Nn && (unsigned)d < (unsigned)Nn)
            atomicAdd(&h[d >> BINSH], 1);
    }
    __syncthreads();
    for (int i = threadIdx.x; i < BINS; i += 256)
        if (h[i]) atomicAdd(&binCnt[i], h[i]);
}

// ---------------- P2: scan bins -> offsets, init cursors, pad CSR ----------------
__global__ __launch_bounds__(512) void bin_scan(const int* __restrict__ binCnt,
                                                int* __restrict__ binOff,
                                                int* __restrict__ binCursor,
                                                int* __restrict__ rowPtr,
                                                int* __restrict__ sortedSrc) {
    __shared__ int a[512];
    int t = threadIdx.x;
    int v = (t < BINS) ? binCnt[t] : 0;
    a[t] = v;
    __syncthreads();
    for (int off = 1; off < 512; off <<= 1) {
        int x = a[t] + ((t >= off) ? a[t - off] : 0);
        __syncthreads();
        a[t] = x;
        __syncthreads();
    }
    if (t < BINS) { binOff[t] = a[t] - v; binCursor[t] = a[t] - v; }
    int E = a[BINS - 1];
    if (t == 0) { binOff[BINS] = E; rowPtr[Nn] = E; }
    if (t < 8) sortedSrc[E + t] = 0;  // pad for unconditional 8-wide reads
}

// ---------------- P3: binning scatter (coalesced run writes) ----------------
__global__ __launch_bounds__(256) void bin_scatter(const int* __restrict__ ei,
                                                   const int* __restrict__ flag,
                                                   int* __restrict__ binCursor,
                                                   unsigned* __restrict__ arena) {
    __shared__ unsigned srec[CHUNK];                       // 32 KB
    __shared__ int bcnt[BINS], bpfx[BINS], bfill[BINS], gbase[BINS];
    __shared__ int pA[512], pB[512];
    const int tid = threadIdx.x;
    const int e0 = blockIdx.x * CHUNK;
    const int n = min(CHUNK, Ee - e0);
    const int f = *flag;

    for (int i = tid; i < BINS; i += 256) { bcnt[i] = 0; bfill[i] = 0; }
    __syncthreads();
    for (int i = tid; i < n; i += 256) {
        int s, d;
        load_edge(ei, f, e0 + i, s, d);
        if ((unsigned)s < (unsigned)Nn && (unsigned)d < (unsigned)Nn)
            atomicAdd(&bcnt[d >> BINSH], 1);
    }
    __syncthreads();
    for (int i = tid; i < 512; i += 256) pA[i] = (i < BINS) ? bcnt[i] : 0;
    __syncthreads();
    int* incl = scan_incl(pA, pB, 512, tid);
    for (int i = tid; i < BINS; i += 256) {
        bpfx[i] = incl[i] - bcnt[i];
        gbase[i] = bcnt[i] ? atomicAdd(&binCursor[i], bcnt[i]) : 0;
    }
    __syncthreads();
    for (int i = tid; i < n; i += 256) {
        int s, d;
        load_edge(ei, f, e0 + i, s, d);
        if ((unsigned)s < (unsigned)Nn && (unsigned)d < (unsigned)Nn) {
            int bin = d >> BINSH;
            int lp = atomicAdd(&bfill[bin], 1);
            srec[bpfx[bin] + lp] = ((unsigned)(d & (BINSZ - 1)) << 17) | (unsigned)s;
        }
    }
    __syncthreads();
    const int wid = tid >> 6, lane = tid & 63;
    for (int bin = wid; bin < BINS; bin += 4) {
        int cnt = bcnt[bin], off = bpfx[bin], gb = gbase[bin];
        for (int j = lane; j < cnt; j += 64) arena[gb + j] = srec[off + j];
    }
}

// ---------------- P4: per-bin finalize -> CSR + rowPtr + dinv ----------------
__global__ __launch_bounds__(256) void bin_finalize(const int* __restrict__ binOff,
                                                    const unsigned* __restrict__ arena,
                                                    int* __restrict__ rowPtr,
                                                    float* __restrict__ dinv,
                                                    int* __restrict__ sortedSrc) {
    __shared__ unsigned seg[SEGCAP];   // 21 KB
    __shared__ int ssrc[SEGCAP];       // 21 KB
    __shared__ int cnt[BINSZ], fill[BINSZ], pA[BINSZ], pB[BINSZ];
    const int tid = threadIdx.x;
    const int b = blockIdx.x;
    const int base = binOff[b];
    int len = binOff[b + 1] - base;
    if (len > SEGCAP) len = SEGCAP;

    for (int i = tid; i < len; i += 256) seg[i] = arena[base + i];
    for (int i = tid; i < BINSZ; i += 256) { cnt[i] = 0; fill[i] = 0; }
    __syncthreads();
    for (int i = tid; i < len; i += 256) atomicAdd(&cnt[seg[i] >> 17], 1);
    __syncthreads();
    for (int i = tid; i < BINSZ; i += 256) pA[i] = cnt[i];
    __syncthreads();
    int* incl = scan_incl(pA, pB, BINSZ, tid);

    const int node0 = b * BINSZ;
    for (int t = tid; t < BINSZ; t += 256) {
        int node = node0 + t;
        if (node < Nn) {
            rowPtr[node] = base + incl[t] - cnt[t];
            dinv[node] = rsqrtf((float)(cnt[t] + 1));  // +1 self loop
        }
    }
    __syncthreads();
    for (int i = tid; i < len; i += 256) {
        unsigned r = seg[i];
        int dl = r >> 17, s = (int)(r & 0x1FFFFu);
        int p = atomicAdd(&fill[dl], 1);
        ssrc[incl[dl] - cnt[dl] + p] = s;
    }
    __syncthreads();
    for (int i = tid; i < len; i += 256) sortedSrc[base + i] = ssrc[i];
}

// ---------------- W transpose + fp16 convert: Wt[c][k] = W[k][c] (conv weights) ----------------
__global__ __launch_bounds__(256) void transpose_w(const float* __restrict__ W0,
                                                   const float* __restrict__ W1,
                                                   const float* __restrict__ W2,
                                                   f16* __restrict__ T) {
    const float* W = (blockIdx.x == 0) ? W0 : ((blockIdx.x == 1) ? W1 : W2);
    f16* Wt = T + (size_t)blockIdx.x * D * D;
    for (int i = threadIdx.x; i < D * D; i += 256) {
        int k = i >> 7, c = i & 127;
        Wt[c * D + k] = (f16)W[i];
    }
}

// ---------------- W_cls transpose+pad: Wct[c][k] (c<48 padded, stride WS) ----------------
__global__ __launch_bounds__(256) void prep_wcls(const float* __restrict__ Wc,
                                                 f16* __restrict__ Wct) {
    for (int i = threadIdx.x; i < CPAD * WS; i += 256) {
        int c = i / WS, k = i - c * WS;
        f16 v = (f16)0.0f;
        if (c < DOUT && k < DCAT) v = (f16)Wc[k * DOUT + c];
        Wct[i] = v;
    }
}

// ---------------- MFMA GEMM: C[M,128](f16,stride sC) = act(A[M,128,stride sA] @ Wt^T (+bias)) * scale ----
// A fragments read directly from global (lane&15 = row, lane>>4 = k-octet: 4 lanes
// consume one 64B row-chunk). B (Wt, pre-transposed [col][k]) staged in LDS with
// XOR swizzle (G4): byte_in_row ^= (row&7)<<4.
template <int AFP32>
__global__ __launch_bounds__(256) void gemm_mfma(const void* __restrict__ Ain, int sA,
                                                 const f16* __restrict__ Wt,
                                                 const float* __restrict__ bias,
                                                 const float* __restrict__ scale,
                                                 f16* __restrict__ C, int sC,
                                                 int M, int doRelu) {
    __shared__ f16 Bsw[128 * 128];  // 32 KB
    const int tid = threadIdx.x;
    const int r0 = blockIdx.x * 128;

    {   // stage B
        int row = tid >> 1, half = (tid & 1) * 128;
#pragma unroll
        for (int i = 0; i < 8; ++i) {
            int bir = half + i * 16;
            uint4 v = *(const uint4*)((const char*)Wt + (size_t)row * 256 + bir);
            *(uint4*)((char*)Bsw + row * 256 + (bir ^ ((row & 7) << 4))) = v;
        }
    }
    __syncthreads();

    const int lane = tid & 63;
    const int w    = tid >> 6;
    const int wr   = w * 32;

    f32x4 acc[2][8];
#pragma unroll
    for (int mf = 0; mf < 2; ++mf)
#pragma unroll
        for (int nf = 0; nf < 8; ++nf) acc[mf][nf] = (f32x4){0, 0, 0, 0};

#pragma unroll
    for (int kk = 0; kk < 4; ++kk) {
        const int ke = kk * 32 + (lane >> 4) * 8;  // k element offset for this lane
        f16x8 a[2], b[8];
#pragma unroll
        for (int mf = 0; mf < 2; ++mf) {
            int row = r0 + wr + mf * 16 + (lane & 15);
            int rc = (row < M) ? row : (M - 1);  // clamp; OOB rows never stored
            if (AFP32) {
                const float* p = (const float*)Ain + (size_t)rc * sA + ke;
                float4 f0 = *(const float4*)p;
                float4 f1 = *(const float4*)(p + 4);
                f16x8 h;
                h[0] = (f16)f0.x; h[1] = (f16)f0.y; h[2] = (f16)f0.z; h[3] = (f16)f0.w;
                h[4] = (f16)f1.x; h[5] = (f16)f1.y; h[6] = (f16)f1.z; h[7] = (f16)f1.w;
                a[mf] = h;
            } else {
                a[mf] = *(const f16x8*)((const f16*)Ain + (size_t)rc * sA + ke);
            }
        }
#pragma unroll
        for (int nf = 0; nf < 8; ++nf) {
            int col = nf * 16 + (lane & 15);
            int bir = kk * 64 + (lane >> 4) * 16;
            b[nf] = *(const f16x8*)((const char*)Bsw + col * 256 + (bir ^ ((col & 7) << 4)));
        }
#pragma unroll
        for (int mf = 0; mf < 2; ++mf)
#pragma unroll
            for (int nf = 0; nf < 8; ++nf)
                acc[mf][nf] = __builtin_amdgcn_mfma_f32_16x16x32_f16(a[mf], b[nf], acc[mf][nf], 0, 0, 0);
    }

    float bv[8];
#pragma unroll
    for (int nf = 0; nf < 8; ++nf) bv[nf] = bias ? bias[nf * 16 + (lane & 15)] : 0.0f;
#pragma unroll
    for (int mf = 0; mf < 2; ++mf) {
#pragma unroll
        for (int i = 0; i < 4; ++i) {
            int row = r0 + wr + mf * 16 + (lane >> 4) * 4 + i;
            if (row < M) {
                float sc = scale ? scale[row] : 1.0f;
#pragma unroll
                for (int nf = 0; nf < 8; ++nf) {
                    float v = acc[mf][nf][i] + bv[nf];
                    if (doRelu && v < 0.0f) v = 0.0f;
                    C[(size_t)row * sC + nf * 16 + (lane & 15)] = (f16)(v * sc);
                }
            }
        }
    }
}

// ---------------- CSR aggregation (tmp pre-scaled by dinv[src]) ----------------
// hcat[i][partOff..] = relu( dinv[i] * ( sum_{s in N(i)} tmp[s] + tmp[i] ) + b )
__global__ __launch_bounds__(256) void aggregate_csr(const f16* __restrict__ tmp,
                                                     const int* __restrict__ rowPtr,
                                                     const int* __restrict__ sortedSrc,
                                                     const float* __restrict__ dinv,
                                                     const float* __restrict__ bias,
                                                     f16* __restrict__ hcat, int partOff) {
    int node = (blockIdx.x * 256 + threadIdx.x) >> 6;  // one wave per node
    int lane = threadIdx.x & 63;
    if (node >= Nn) return;
    const f16x2* t2 = (const f16x2*)tmp;

    int base = rowPtr[node];
    int c = rowPtr[node + 1] - base;
    float di = dinv[node];

    f16x2 sv = t2[(size_t)node * 64 + lane];  // self (already *dinv[node])
    float ax = (float)sv[0];
    float ay = (float)sv[1];

    for (int e = 0; e < c; e += 8) {
        int s[8];
        f16x2 v[8];
#pragma unroll
        for (int k = 0; k < 8; ++k) {
            int raw = sortedSrc[base + e + k];       // safe: 8-padded
            s[k] = (e + k < c) ? raw : 0;
        }
#pragma unroll
        for (int k = 0; k < 8; ++k) v[k] = t2[(size_t)s[k] * 64 + lane];  // 8 gathers in flight
#pragma unroll
        for (int k = 0; k < 8; ++k) {
            bool m = (e + k) < c;
            ax += m ? (float)v[k][0] : 0.0f;
            ay += m ? (float)v[k][1] : 0.0f;
        }
    }

    float2 bb = ((const float2*)bias)[lane];
    ax = di * ax + bb.x;
    ay = di * ay + bb.y;
    if (ax < 0.0f) ax = 0.0f;
    if (ay < 0.0f) ay = 0.0f;
    f16x2 o;
    o[0] = (f16)ax;
    o[1] = (f16)ay;
    *(f16x2*)(hcat + (size_t)node * DCAT + partOff + lane * 2) = o;
}

// ---------------- MFMA classifier: out[N,40] = hcat[N,384] @ Wct^T + b ----------------
__global__ __launch_bounds__(256) void cls_mfma(const f16* __restrict__ hcat,
                                                const f16* __restrict__ Wct,
                                                const float* __restrict__ bc,
                                                float* __restrict__ out) {
    __shared__ f16 Bs[CPAD * WS];  // 37.6 KB
    const int tid = threadIdx.x;
    for (int i = tid; i < CPAD * WS / 8; i += 256)
        ((uint4*)Bs)[i] = ((const uint4*)Wct)[i];
    __syncthreads();

    const int lane = tid & 63;
    const int w    = tid >> 6;
    const int r0   = blockIdx.x * 128 + w * 32;

    f32x4 acc[2][3];
#pragma unroll
    for (int mf = 0; mf < 2; ++mf)
#pragma unroll
        for (int nf = 0; nf < 3; ++nf) acc[mf][nf] = (f32x4){0, 0, 0, 0};

#pragma unroll 3
    for (int kk = 0; kk < 12; ++kk) {
        const int ke = kk * 32 + (lane >> 4) * 8;
        f16x8 a[2], b[3];
#pragma unroll
        for (int mf = 0; mf < 2; ++mf) {
            int row = r0 + mf * 16 + (lane & 15);
            int rc = (row < Nn) ? row : (Nn - 1);
            a[mf] = *(const f16x8*)(hcat + (size_t)rc * DCAT + ke);
        }
#pragma unroll
        for (int nf = 0; nf < 3; ++nf) {
            int col = nf * 16 + (lane & 15);
            b[nf] = *(const f16x8*)(Bs + col * WS + ke);
        }
#pragma unroll
        for (int mf = 0; mf < 2; ++mf)
#pragma unroll
            for (int nf = 0; nf < 3; ++nf)
                acc[mf][nf] = __builtin_amdgcn_mfma_f32_16x16x32_f16(a[mf], b[nf], acc[mf][nf], 0, 0, 0);
    }

    float bv[3];
#pragma unroll
    for (int nf = 0; nf < 3; ++nf) {
        int col = nf * 16 + (lane & 15);
        bv[nf] = (col < DOUT) ? bc[col] : 0.0f;
    }
#pragma unroll
    for (int mf = 0; mf < 2; ++mf) {
#pragma unroll
        for (int i = 0; i < 4; ++i) {
            int row = r0 + mf * 16 + (lane >> 4) * 4 + i;
            if (row < Nn) {
#pragma unroll
                for (int nf = 0; nf < 3; ++nf) {
                    int col = nf * 16 + (lane & 15);
                    if (col < DOUT) out[(size_t)row * DOUT + col] = acc[mf][nf][i] + bv[nf];
                }
            }
        }
    }
}

// ---------------- launch ----------------
extern "C" void kernel_launch(void* const* d_in, const int* in_sizes, int n_in,
                              void* d_out, int out_size, void* d_ws, size_t ws_size,
                              hipStream_t stream) {
    const float* x       = (const float*)d_in[0];
    const int*   ei      = (const int*)d_in[1];
    const float* W_embed = (const float*)d_in[2];
    const float* b_embed = (const float*)d_in[3];
    const float* W_conv1 = (const float*)d_in[4];
    const float* b_conv1 = (const float*)d_in[5];
    const float* W_conv2 = (const float*)d_in[6];
    const float* b_conv2 = (const float*)d_in[7];
    const float* W_cls   = (const float*)d_in[8];
    const float* b_cls   = (const float*)d_in[9];
    float* out = (float*)d_out;

    char* p = (char*)d_ws;
    size_t o = 0;
    auto carve = [&](size_t bytes) {
        char* r = p + o;
        o = (o + bytes + 255) & ~(size_t)255;
        return r;
    };
    int*      binCnt    = (int*)carve((size_t)BINS * 4);
    int*      binOff    = (int*)carve((size_t)(BINS + 1) * 4);
    int*      binCursor = (int*)carve((size_t)BINS * 4);
    unsigned* arena     = (unsigned*)carve((size_t)Ee * 4);
    int*      rowPtr    = (int*)carve((size_t)(Nn + 1) * 4);
    int*      sortedSrc = (int*)carve((size_t)(Ee + 8) * 4);
    float*    dinv      = (float*)carve((size_t)Nn * 4);
    int*      flag      = (int*)carve(4);
    f16*      WtAll     = (f16*)carve((size_t)3 * D * D * 2);
    f16*      Wct       = (f16*)carve((size_t)CPAD * WS * 2);
    f16*      hcat      = (f16*)carve((size_t)Nn * DCAT * 2);  // 76.8 MB
    f16*      tmp       = (f16*)carve((size_t)Nn * D * 2);
    (void)ws_size;

    hipMemsetAsync(binCnt, 0, (size_t)BINS * 4, stream);
    detect_layout<<<1, 64, 0, stream>>>(ei, flag);
    bin_hist<<<512, 256, 0, stream>>>(ei, flag, binCnt);
    bin_scan<<<1, 512, 0, stream>>>(binCnt, binOff, binCursor, rowPtr, sortedSrc);
    bin_scatter<<<NCHUNK, 256, 0, stream>>>(ei, flag, binCursor, arena);
    bin_finalize<<<BINS, 256, 0, stream>>>(binOff, arena, rowPtr, dinv, sortedSrc);
    transpose_w<<<3, 256, 0, stream>>>(W_embed, W_conv1, W_conv2, WtAll);
    prep_wcls<<<1, 256, 0, stream>>>(W_cls, Wct);

    const int gGemm = (Nn + 127) / 128;
    const int gAgg  = (Nn * 64) / 256;

    // h0 = relu(x @ W_embed + b_embed)  -> hcat part 0
    gemm_mfma<1><<<gGemm, 256, 0, stream>>>(x, D, WtAll, b_embed, nullptr, hcat, DCAT, Nn, 1);
    // conv1: tmp = (h0 @ W1) * dinv ; h1 = relu(dinv*(agg+self) + b1) -> hcat part 1
    gemm_mfma<0><<<gGemm, 256, 0, stream>>>(hcat, DCAT, WtAll + D * D, nullptr, dinv, tmp, D, Nn, 0);
    aggregate_csr<<<gAgg, 256, 0, stream>>>(tmp, rowPtr, sortedSrc, dinv, b_conv1, hcat, D);
    // conv2 -> hcat part 2
    gemm_mfma<0><<<gGemm, 256, 0, stream>>>(hcat + D, DCAT, WtAll + 2 * D * D, nullptr, dinv, tmp, D, Nn, 0);
    aggregate_csr<<<gAgg, 256, 0, stream>>>(tmp, rowPtr, sortedSrc, dinv, b_conv2, hcat, 2 * D);
    // classifier (MFMA over concat)
    cls_mfma<<<gGemm, 256, 0, stream>>>(hcat, Wct, b_cls, out);
}